// Round 2
// baseline (197.986 us; speedup 1.0000x reference)
//
#include <hip/hip_runtime.h>
#include <math.h>

#define EPS 1e-8f
#define HALF_BIN 0.05f
#define TILE 512   // elements per LDS tile: 2 KB per stream, 256 threads -> 2 elem/thread

// pd = sigmoid(xu) - sigmoid(xl), xu >= xl, one reciprocal:
//   e_u = exp(-xu), e_l = exp(-xl);  pd = (e_l - e_u) / ((1+e_u)(1+e_l))
// exp args clamped <= 87 so e is finite; saturated cases -> den inf -> pd 0,
// matching the reference's (0 - 0) there.
__device__ __forceinline__ float sigmoid_diff(float xu, float xl) {
    float eu = __expf(fminf(-xu, 87.0f));
    float el = __expf(fminf(-xl, 87.0f));
    float num = el - eu;
    float den = (1.0f + eu) * (1.0f + el);
    return __fdividef(num, den);
}

// async global->LDS, 16 B per lane. HW semantics: per-lane GLOBAL src address,
// wave-uniform LDS dst base + lane*16 (pass the uniform base).
__device__ __forceinline__ void gload_lds16(const float* gsrc, float* ldst) {
    __builtin_amdgcn_global_load_lds(
        (const __attribute__((address_space(1))) void*)gsrc,
        (__attribute__((address_space(3))) void*)ldst,
        16 /*bytes per lane, literal*/, 0 /*offset*/, 0 /*aux*/);
}

__device__ __forceinline__ void elem_math(
    float pvj, float tj, float lik,
    float& bce, float& ll, float& npaid)
{
    bool paid = tj > 0.0f;
    float val = paid ? pvj : (1.0f - pvj);
    bce -= fmaxf(__logf(val), -100.0f);
    float lg = __logf(lik + EPS);
    ll    += paid ? lg : 0.0f;
    npaid += paid ? 1.0f : 0.0f;
}

template <int K>
__device__ __forceinline__ void process_elem(
    float pv, float t, const float* mu, const float* sigma, const float* weight,
    size_t i, size_t B, float& bce, float& ll, float& npaid)
{
    float lik = 0.0f;
    #pragma unroll
    for (int k = 0; k < K; ++k) {
        size_t off = (size_t)k * B + i;
        float inv_s = __fdividef(1.0f, sigma[off] + EPS);
        float xu = (t + HALF_BIN - mu[off]) * inv_s;
        float xl = (t - HALF_BIN - mu[off]) * inv_s;
        float pd = fmaxf(sigmoid_diff(xu, xl), EPS);
        lik = fmaf(weight[off], pd, lik);
    }
    elem_math(pv, t, lik, bce, ll, npaid);
}

// R2: LDS-staged streaming. Rationale: at VGPR=44 the compiler provably keeps
// only ~4-6 of the 22 per-trip loads in flight (register recycling); R1 showed
// more waves does NOT raise BW (2048 blk was 11% WORSE than 1024). So amplify
// per-wave MLP without VGPRs: global_load_lds DMA posts all 22 staging units
// (11 streams x 2 x 1KB) per tile with zero register cost, in contiguous 2KB
// bursts per stream. Double-buffered 2x22KB LDS -> 3 blocks/CU.
template <int K>
__global__ __launch_bounds__(256) void zimol_main(
    const float* __restrict__ p,
    const float* __restrict__ mu,
    const float* __restrict__ sigma,
    const float* __restrict__ weight,
    const float* __restrict__ tv,
    float* __restrict__ part_bce,
    float* __restrict__ part_ll,
    float* __restrict__ part_n,
    int B)
{
    constexpr int NS = 3 * K + 2;          // streams: p, tv, K x (mu, sigma, w)
    __shared__ __align__(16) float lds[2][NS][TILE];
    __shared__ float sdata[3][4];

    const int lane = threadIdx.x & 63;
    const int wave = threadIdx.x >> 6;

    const float* bases[NS];
    bases[0] = p;
    bases[1] = tv;
    #pragma unroll
    for (int k = 0; k < K; ++k) {
        bases[2 + 3 * k] = mu     + (size_t)k * (size_t)B;
        bases[3 + 3 * k] = sigma  + (size_t)k * (size_t)B;
        bases[4 + 3 * k] = weight + (size_t)k * (size_t)B;
    }

    float bce = 0.0f, ll = 0.0f, npaid = 0.0f;

    const int ntiles = B / TILE;
    const int tpb = (ntiles + gridDim.x - 1) / gridDim.x;
    const int t0 = blockIdx.x * tpb;
    const int t1 = (t0 + tpb < ntiles) ? (t0 + tpb) : ntiles;

    // stage one tile: 2*NS units of 1 KB (256 floats); unit u -> stream u>>1,
    // half u&1. Unrolled so bases[s]/lds[..][s] are compile-time indexed
    // (rule #20); the (u&3)==wave guard is wave-uniform.
    auto stage = [&](int buf, int t) {
        const int e0 = t * TILE;
        #pragma unroll
        for (int u = 0; u < 2 * NS; ++u) {
            if ((u & 3) == wave) {
                const int s = u >> 1;
                const int h = u & 1;
                gload_lds16(bases[s] + e0 + h * 256 + lane * 4,
                            &lds[buf][s][h * 256]);
            }
        }
    };

    if (t0 < t1) {
        stage(0, t0);
        int cur = 0;
        for (int t = t0; t < t1; ++t) {
            // compiler emits s_waitcnt vmcnt(0) before s_barrier: drains the
            // stage of buf[cur] (and any in-flight next-stage) -> LDS visible.
            __syncthreads();
            if (t + 1 < t1) stage(cur ^ 1, t + 1);   // overlap with compute

            const int e = threadIdx.x * 2;           // 2 elems/thread
            const float2 pv = *(const float2*)&lds[cur][0][e];
            const float2 tvv = *(const float2*)&lds[cur][1][e];
            float lik0 = 0.0f, lik1 = 0.0f;
            #pragma unroll
            for (int k = 0; k < K; ++k) {
                const float2 m = *(const float2*)&lds[cur][2 + 3 * k][e];
                const float2 s = *(const float2*)&lds[cur][3 + 3 * k][e];
                const float2 w = *(const float2*)&lds[cur][4 + 3 * k][e];
                {
                    float inv_s = __fdividef(1.0f, s.x + EPS);
                    float xu = (tvv.x + HALF_BIN - m.x) * inv_s;
                    float xl = (tvv.x - HALF_BIN - m.x) * inv_s;
                    lik0 = fmaf(w.x, fmaxf(sigmoid_diff(xu, xl), EPS), lik0);
                }
                {
                    float inv_s = __fdividef(1.0f, s.y + EPS);
                    float xu = (tvv.y + HALF_BIN - m.y) * inv_s;
                    float xl = (tvv.y - HALF_BIN - m.y) * inv_s;
                    lik1 = fmaf(w.y, fmaxf(sigmoid_diff(xu, xl), EPS), lik1);
                }
            }
            elem_math(pv.x, tvv.x, lik0, bce, ll, npaid);
            elem_math(pv.y, tvv.y, lik1, bce, ll, npaid);
            cur ^= 1;
        }
    }

    // leftover elements [ntiles*TILE, B): grid-stride scalar path (tiny/empty)
    {
        const int base = ntiles * TILE;
        for (int i = base + blockIdx.x * blockDim.x + threadIdx.x; i < B;
             i += gridDim.x * blockDim.x) {
            process_elem<K>(p[i], tv[i], mu, sigma, weight,
                            (size_t)i, (size_t)B, bce, ll, npaid);
        }
    }

    // wave-level reduction (wave = 64 lanes)
    #pragma unroll
    for (int off = 32; off > 0; off >>= 1) {
        bce   += __shfl_down(bce,   off, 64);
        ll    += __shfl_down(ll,    off, 64);
        npaid += __shfl_down(npaid, off, 64);
    }

    if (lane == 0) {
        sdata[0][wave] = bce;
        sdata[1][wave] = ll;
        sdata[2][wave] = npaid;
    }
    __syncthreads();
    if (threadIdx.x == 0) {
        float b = 0.0f, l = 0.0f, n = 0.0f;
        #pragma unroll
        for (int w = 0; w < 4; ++w) {
            b += sdata[0][w];
            l += sdata[1][w];
            n += sdata[2][w];
        }
        part_bce[blockIdx.x] = b;
        part_ll [blockIdx.x] = l;
        part_n  [blockIdx.x] = n;
    }
}

__global__ __launch_bounds__(256) void zimol_reduce(
    const float* __restrict__ part_bce,
    const float* __restrict__ part_ll,
    const float* __restrict__ part_n,
    float* __restrict__ out, int nblocks, int B)
{
    double b = 0.0, l = 0.0, n = 0.0;
    for (int i = threadIdx.x; i < nblocks; i += 256) {
        b += (double)part_bce[i];
        l += (double)part_ll[i];
        n += (double)part_n[i];
    }
    #pragma unroll
    for (int off = 32; off > 0; off >>= 1) {
        b += __shfl_down(b, off, 64);
        l += __shfl_down(l, off, 64);
        n += __shfl_down(n, off, 64);
    }
    __shared__ double sdata[3][4];
    const int wave = threadIdx.x >> 6;
    const int lane = threadIdx.x & 63;
    if (lane == 0) {
        sdata[0][wave] = b;
        sdata[1][wave] = l;
        sdata[2][wave] = n;
    }
    __syncthreads();
    if (threadIdx.x == 0) {
        double tb = 0.0, tl = 0.0, tn = 0.0;
        #pragma unroll
        for (int w = 0; w < 4; ++w) {
            tb += sdata[0][w];
            tl += sdata[1][w];
            tn += sdata[2][w];
        }
        double purchase = tb / (double)B;
        double ltv = (tn > 0.0) ? -(tl / fmax(tn, 1.0)) : 0.0;
        out[0] = (float)(purchase + ltv);
    }
}

extern "C" void kernel_launch(void* const* d_in, const int* in_sizes, int n_in,
                              void* d_out, int out_size, void* d_ws, size_t ws_size,
                              hipStream_t stream) {
    const float* p      = (const float*)d_in[0];
    const float* mu     = (const float*)d_in[1];
    const float* sigma  = (const float*)d_in[2];
    const float* weight = (const float*)d_in[3];
    const float* tv     = (const float*)d_in[4];
    float* out = (float*)d_out;

    const int B = in_sizes[0];
    const int K = in_sizes[1] / B;

    const int threads = 256;
    // 768 blocks = 3 blocks/CU (LDS-capped at ~45 KB/block for K=3).
    // Block-chunked contiguous tile assignment for sequential per-stream bursts.
    int ntiles = B / TILE;
    int blocks;
    if (ntiles > 0) {
        blocks = (ntiles < 768) ? ntiles : 768;
    } else {
        blocks = (B + threads - 1) / threads;
        if (blocks > 768) blocks = 768;
    }
    if (blocks < 1) blocks = 1;

    float* part_bce = (float*)d_ws;
    float* part_ll  = part_bce + blocks;
    float* part_n   = part_ll  + blocks;

    if (K == 3) {
        zimol_main<3><<<blocks, threads, 0, stream>>>(p, mu, sigma, weight, tv,
                                                      part_bce, part_ll, part_n, B);
    } else if (K == 1) {
        zimol_main<1><<<blocks, threads, 0, stream>>>(p, mu, sigma, weight, tv,
                                                      part_bce, part_ll, part_n, B);
    } else if (K == 2) {
        zimol_main<2><<<blocks, threads, 0, stream>>>(p, mu, sigma, weight, tv,
                                                      part_bce, part_ll, part_n, B);
    } else {
        zimol_main<4><<<blocks, threads, 0, stream>>>(p, mu, sigma, weight, tv,
                                                      part_bce, part_ll, part_n, B);
    }

    zimol_reduce<<<1, threads, 0, stream>>>(part_bce, part_ll, part_n, out, blocks, B);
}

// Round 3
// 176.887 us; speedup vs baseline: 1.1193x; 1.1193x over previous
//
#include <hip/hip_runtime.h>
#include <math.h>

#define EPS 1e-8f
#define HALF_BIN 0.05f

// clang ext-vector so __builtin_nontemporal_load is legal (HIP float4 is a
// struct; the builtin requires scalar/vector type).
typedef float v4f __attribute__((ext_vector_type(4)));

__device__ __forceinline__ v4f ntload4(const v4f* p) {
    return __builtin_nontemporal_load(p);
}

// pd = sigmoid(xu) - sigmoid(xl), xu >= xl, computed with one reciprocal:
//   e_u = exp(-xu), e_l = exp(-xl)
//   pd  = (e_l - e_u) / ((1+e_u)(1+e_l))
// exp args clamped to <= 87 so e is finite; saturated cases give den->inf ->
// rcp 0 -> pd 0, matching the reference's (0 - 0) there.
__device__ __forceinline__ float sigmoid_diff(float xu, float xl) {
    float eu = __expf(fminf(-xu, 87.0f));
    float el = __expf(fminf(-xl, 87.0f));
    float num = el - eu;
    float den = (1.0f + eu) * (1.0f + el);
    return __fdividef(num, den);
}

// buf layout per group: [0]=p, [1]=tv, then for k: [2+3k]=mu, [3+3k]=sigma, [4+3k]=weight
template <int K>
__device__ __forceinline__ void process_group_buf(
    const v4f (&buf)[3 * K + 2],
    float& bce, float& ll, float& npaid)
{
    float pv[4] = {buf[0].x, buf[0].y, buf[0].z, buf[0].w};
    float t [4] = {buf[1].x, buf[1].y, buf[1].z, buf[1].w};
    float lik[4] = {0.0f, 0.0f, 0.0f, 0.0f};

    #pragma unroll
    for (int k = 0; k < K; ++k) {
        const v4f mf = buf[2 + 3 * k];
        const v4f sf = buf[3 + 3 * k];
        const v4f wf = buf[4 + 3 * k];
        float m[4] = {mf.x, mf.y, mf.z, mf.w};
        float s[4] = {sf.x, sf.y, sf.z, sf.w};
        float w[4] = {wf.x, wf.y, wf.z, wf.w};
        #pragma unroll
        for (int j = 0; j < 4; ++j) {
            float inv_s = __fdividef(1.0f, s[j] + EPS);
            float xu = (t[j] + HALF_BIN - m[j]) * inv_s;
            float xl = (t[j] - HALF_BIN - m[j]) * inv_s;
            float pd = fmaxf(sigmoid_diff(xu, xl), EPS);
            lik[j] = fmaf(w[j], pd, lik[j]);
        }
    }

    #pragma unroll
    for (int j = 0; j < 4; ++j) {
        bool paid = t[j] > 0.0f;
        float val = paid ? pv[j] : (1.0f - pv[j]);
        bce -= fmaxf(__logf(val), -100.0f);
        float lg = __logf(lik[j] + EPS);
        ll    += paid ? lg : 0.0f;
        npaid += paid ? 1.0f : 0.0f;
    }
}

template <int K>
__device__ __forceinline__ void process_elem(
    float pv, float t, const float* mu, const float* sigma, const float* weight,
    size_t i, size_t B, float& bce, float& ll, float& npaid)
{
    float lik = 0.0f;
    #pragma unroll
    for (int k = 0; k < K; ++k) {
        size_t off = (size_t)k * B + i;
        float inv_s = __fdividef(1.0f, sigma[off] + EPS);
        float xu = (t + HALF_BIN - mu[off]) * inv_s;
        float xl = (t - HALF_BIN - mu[off]) * inv_s;
        float pd = fmaxf(sigmoid_diff(xu, xl), EPS);
        lik = fmaf(weight[off], pd, lik);
    }
    bool paid = t > 0.0f;
    float val = paid ? pv : (1.0f - pv);
    bce -= fmaxf(__logf(val), -100.0f);
    float lg = __logf(lik + EPS);
    ll    += paid ? lg : 0.0f;
    npaid += paid ? 1.0f : 0.0f;
}

// R3: identical structure to the 71.5us R0 kernel (1024 blocks, reg-buffered,
// 2-way ILP) with ONE change: all hot-loop loads are NON-TEMPORAL.
// Rationale: R0/R1/R2 (reg x1024, reg x2048, LDS-DMA x768) all plateau at
// ~2.4-2.6 TB/s effective = 128 B/cy/XCD = one L2-line allocation per cycle
// per XCD. Zero-reuse streaming data should not allocate -> nt bit.
template <int K>
__global__ __launch_bounds__(256, 4) void zimol_main(
    const float* __restrict__ p,
    const float* __restrict__ mu,
    const float* __restrict__ sigma,
    const float* __restrict__ weight,
    const float* __restrict__ tv,
    float* __restrict__ part_bce,
    float* __restrict__ part_ll,
    float* __restrict__ part_n,
    int B)
{
    const int tid    = blockIdx.x * blockDim.x + threadIdx.x;
    const int stride = gridDim.x * blockDim.x;

    float bce = 0.0f, ll = 0.0f, npaid = 0.0f;

    if ((B & 3) == 0) {
        const int B4 = B >> 2;
        const v4f* __restrict__ p4  = (const v4f*)p;
        const v4f* __restrict__ tv4 = (const v4f*)tv;
        const v4f* __restrict__ mu4 = (const v4f*)mu;
        const v4f* __restrict__ sg4 = (const v4f*)sigma;
        const v4f* __restrict__ wt4 = (const v4f*)weight;

        constexpr int NB = 3 * K + 2;   // v4f's per group
        int i = tid;
        // two independent groups per trip; all 2*NB loads issued before compute
        for (; i + stride < B4; i += 2 * stride) {
            v4f buf[2][NB];
            #pragma unroll
            for (int u = 0; u < 2; ++u) {
                const int idx = i + u * stride;
                buf[u][0] = ntload4(p4  + idx);
                buf[u][1] = ntload4(tv4 + idx);
                #pragma unroll
                for (int k = 0; k < K; ++k) {
                    const size_t off = (size_t)k * (size_t)B4;
                    buf[u][2 + 3 * k] = ntload4(mu4 + off + idx);
                    buf[u][3 + 3 * k] = ntload4(sg4 + off + idx);
                    buf[u][4 + 3 * k] = ntload4(wt4 + off + idx);
                }
            }
            process_group_buf<K>(buf[0], bce, ll, npaid);
            process_group_buf<K>(buf[1], bce, ll, npaid);
        }
        // remaining single groups
        for (; i < B4; i += stride) {
            v4f buf[NB];
            buf[0] = ntload4(p4  + i);
            buf[1] = ntload4(tv4 + i);
            #pragma unroll
            for (int k = 0; k < K; ++k) {
                const size_t off = (size_t)k * (size_t)B4;
                buf[2 + 3 * k] = ntload4(mu4 + off + i);
                buf[3 + 3 * k] = ntload4(sg4 + off + i);
                buf[4 + 3 * k] = ntload4(wt4 + off + i);
            }
            process_group_buf<K>(buf, bce, ll, npaid);
        }
    } else {
        for (int i = tid; i < B; i += stride) {
            process_elem<K>(p[i], tv[i], mu, sigma, weight,
                            (size_t)i, (size_t)B, bce, ll, npaid);
        }
    }

    // wave-level reduction (wave = 64 lanes)
    #pragma unroll
    for (int off = 32; off > 0; off >>= 1) {
        bce   += __shfl_down(bce,   off, 64);
        ll    += __shfl_down(ll,    off, 64);
        npaid += __shfl_down(npaid, off, 64);
    }

    __shared__ float sdata[3][4];
    const int wave = threadIdx.x >> 6;
    const int lane = threadIdx.x & 63;
    if (lane == 0) {
        sdata[0][wave] = bce;
        sdata[1][wave] = ll;
        sdata[2][wave] = npaid;
    }
    __syncthreads();
    if (threadIdx.x == 0) {
        float b = 0.0f, l = 0.0f, n = 0.0f;
        #pragma unroll
        for (int w = 0; w < 4; ++w) {
            b += sdata[0][w];
            l += sdata[1][w];
            n += sdata[2][w];
        }
        part_bce[blockIdx.x] = b;
        part_ll [blockIdx.x] = l;
        part_n  [blockIdx.x] = n;
    }
}

__global__ __launch_bounds__(256) void zimol_reduce(
    const float* __restrict__ part_bce,
    const float* __restrict__ part_ll,
    const float* __restrict__ part_n,
    float* __restrict__ out, int nblocks, int B)
{
    double b = 0.0, l = 0.0, n = 0.0;
    for (int i = threadIdx.x; i < nblocks; i += 256) {
        b += (double)part_bce[i];
        l += (double)part_ll[i];
        n += (double)part_n[i];
    }
    #pragma unroll
    for (int off = 32; off > 0; off >>= 1) {
        b += __shfl_down(b, off, 64);
        l += __shfl_down(l, off, 64);
        n += __shfl_down(n, off, 64);
    }
    __shared__ double sdata[3][4];
    const int wave = threadIdx.x >> 6;
    const int lane = threadIdx.x & 63;
    if (lane == 0) {
        sdata[0][wave] = b;
        sdata[1][wave] = l;
        sdata[2][wave] = n;
    }
    __syncthreads();
    if (threadIdx.x == 0) {
        double tb = 0.0, tl = 0.0, tn = 0.0;
        #pragma unroll
        for (int w = 0; w < 4; ++w) {
            tb += sdata[0][w];
            tl += sdata[1][w];
            tn += sdata[2][w];
        }
        double purchase = tb / (double)B;
        double ltv = (tn > 0.0) ? -(tl / fmax(tn, 1.0)) : 0.0;
        out[0] = (float)(purchase + ltv);
    }
}

extern "C" void kernel_launch(void* const* d_in, const int* in_sizes, int n_in,
                              void* d_out, int out_size, void* d_ws, size_t ws_size,
                              hipStream_t stream) {
    const float* p      = (const float*)d_in[0];
    const float* mu     = (const float*)d_in[1];
    const float* sigma  = (const float*)d_in[2];
    const float* weight = (const float*)d_in[3];
    const float* tv     = (const float*)d_in[4];
    float* out = (float*)d_out;

    const int B = in_sizes[0];
    const int K = in_sizes[1] / B;

    const int threads = 256;
    // 1024 blocks (R0 best config; R1 showed 2048 is 11% worse).
    int work = ((B + 3) >> 2);
    int blocks = (work + threads - 1) / threads;
    if (blocks > 1024) blocks = 1024;
    if (blocks < 1) blocks = 1;

    float* part_bce = (float*)d_ws;
    float* part_ll  = part_bce + blocks;
    float* part_n   = part_ll  + blocks;

    if (K == 3) {
        zimol_main<3><<<blocks, threads, 0, stream>>>(p, mu, sigma, weight, tv,
                                                      part_bce, part_ll, part_n, B);
    } else if (K == 1) {
        zimol_main<1><<<blocks, threads, 0, stream>>>(p, mu, sigma, weight, tv,
                                                      part_bce, part_ll, part_n, B);
    } else if (K == 2) {
        zimol_main<2><<<blocks, threads, 0, stream>>>(p, mu, sigma, weight, tv,
                                                      part_bce, part_ll, part_n, B);
    } else {
        zimol_main<4><<<blocks, threads, 0, stream>>>(p, mu, sigma, weight, tv,
                                                      part_bce, part_ll, part_n, B);
    }

    zimol_reduce<<<1, threads, 0, stream>>>(part_bce, part_ll, part_n, out, blocks, B);
}